// Round 10
// baseline (324.510 us; speedup 1.0000x reference)
//
#include <hip/hip_runtime.h>
#include <cstdint>
#include <cstddef>

typedef unsigned short u16;
typedef unsigned int   u32;
typedef __bf16 bf16x8 __attribute__((ext_vector_type(8)));
typedef float  f32x4  __attribute__((ext_vector_type(4)));
typedef u16    u16x4  __attribute__((ext_vector_type(4)));

#define BS   8192
#define DIMM 512
#define NH   8
#define HD   64
#define SEQ  2048
#define DFF  2048
#define NQKV 1536

// async global->LDS, 16B/lane; LDS dest = wave-uniform base + lane*16
#define GLD16(g, l) __builtin_amdgcn_global_load_lds( \
    (__attribute__((address_space(1))) const void*)(g), \
    (__attribute__((address_space(3))) void*)(l), 16, 0, 0)

__device__ __forceinline__ float b2f(u16 s) {
  u32 u = ((u32)s) << 16;
  float f; __builtin_memcpy(&f, &u, 4); return f;
}
__device__ __forceinline__ u16 f2b(float f) {
  u32 u; __builtin_memcpy(&u, &f, 4);
  u += 0x7fffu + ((u >> 16) & 1u);   // RNE
  return (u16)(u >> 16);
}
__device__ __forceinline__ u16 f2b_rtz(float f) {
  u32 u; __builtin_memcpy(&u, &f, 4);
  return (u16)(u >> 16);            // truncate; bias cancels in softmax norm
}

// ---- merged weight transpose+convert: 4 weights, one launch ---------------
#define SZ_QKV (DIMM * NQKV)
#define SZ_PRJ (DIMM * DIMM)
#define SZ_F1  (DIMM * DFF)
#define SZ_F2  (DFF * DIMM)
__global__ __launch_bounds__(256) void transpose_all_k(
    const float* __restrict__ w_qkv, const float* __restrict__ w_prj,
    const float* __restrict__ w_f1,  const float* __restrict__ w_f2,
    u16* __restrict__ o_qkv, u16* __restrict__ o_prj,
    u16* __restrict__ o_f1,  u16* __restrict__ o_f2) {
  int idx = blockIdx.x * 256 + threadIdx.x;
  const float* W; u16* O; int Kd, Nd, off;
  if (idx < SZ_QKV)                         { W = w_qkv; O = o_qkv; Kd = DIMM; Nd = NQKV; off = idx; }
  else if (idx < SZ_QKV + SZ_PRJ)           { W = w_prj; O = o_prj; Kd = DIMM; Nd = DIMM; off = idx - SZ_QKV; }
  else if (idx < SZ_QKV + SZ_PRJ + SZ_F1)   { W = w_f1;  O = o_f1;  Kd = DIMM; Nd = DFF;  off = idx - SZ_QKV - SZ_PRJ; }
  else                                      { W = w_f2;  O = o_f2;  Kd = DFF;  Nd = DIMM; off = idx - SZ_QKV - SZ_PRJ - SZ_F1; }
  int n = off / Kd, k = off - n * Kd;
  O[off] = f2b(W[(size_t)k * Nd + n]);
}

// ---------------- LayerNorm f32 -> bf16 (one wave per 512-row) -------------
__global__ __launch_bounds__(256) void ln_f32b_k(const float* __restrict__ X,
    const float* __restrict__ G, const float* __restrict__ Bb, u16* __restrict__ out) {
  int w = threadIdx.x >> 6, lane = threadIdx.x & 63;
  size_t row = (size_t)blockIdx.x * 4 + w;
  const float* xr = X + row * DIMM;
  float v[8];
  *(float4*)&v[0] = *(const float4*)(xr + lane * 8);
  *(float4*)&v[4] = *(const float4*)(xr + lane * 8 + 4);
  float s = 0.f, s2 = 0.f;
#pragma unroll
  for (int j = 0; j < 8; j++) { s += v[j]; s2 += v[j] * v[j]; }
#pragma unroll
  for (int m = 1; m < 64; m <<= 1) { s += __shfl_xor(s, m); s2 += __shfl_xor(s2, m); }
  float mu = s * (1.f / DIMM);
  float rsd = rsqrtf(s2 * (1.f / DIMM) - mu * mu + 1e-5f);
  float g[8], bb[8];
  *(float4*)&g[0]  = *(const float4*)(G + lane * 8);
  *(float4*)&g[4]  = *(const float4*)(G + lane * 8 + 4);
  *(float4*)&bb[0] = *(const float4*)(Bb + lane * 8);
  *(float4*)&bb[4] = *(const float4*)(Bb + lane * 8 + 4);
  uint4 ov; u16* os = (u16*)&ov;
#pragma unroll
  for (int j = 0; j < 8; j++) os[j] = f2b((v[j] - mu) * rsd * g[j] + bb[j]);
  *(uint4*)(out + row * DIMM + lane * 8) = ov;
}

// -------- MFMA GEMM: C[M,N] = A[M,K](bf16) @ BT[N,K](bf16)^T + bias --------
// TM in {128, 64}. XCD swizzle: contiguous m-bands per XCD.
// EPI 0: f32   EPI 1: f32 (v + f32 resid)   EPI 2: gelu->bf16   EPI 3: bf16
template <int EPI, int TM>
__global__ __launch_bounds__(256) void gemm_bt(const u16* __restrict__ A,
    const u16* __restrict__ BT, const float* __restrict__ bias,
    void* __restrict__ Cout, const float* __restrict__ resid, int N, int Kd) {
  __shared__ u16 a_s[TM * 32];
  __shared__ u16 b_s[128 * 32];
  int t = threadIdx.x, lane = t & 63, w = t >> 6;
  int l15 = lane & 15, quad = lane >> 4;
  int gx = gridDim.x;
  int lid = blockIdx.x + gx * blockIdx.y;
  int per = (gx * gridDim.y) >> 3;
  int nid = (lid & 7) * per + (lid >> 3);
  int bx = nid % gx, by = nid / gx;
  int m0 = by * TM, n0 = bx * 128;
  constexpr int MT = TM / 32;               // mt tiles per wave
  int wm = (w >> 1) * (TM / 2), wn = (w & 1) * 64;
  f32x4 z4 = {0.f, 0.f, 0.f, 0.f};
  f32x4 acc[MT][4];
#pragma unroll
  for (int i = 0; i < MT; i++)
#pragma unroll
    for (int j = 0; j < 4; j++) acc[i][j] = z4;

  for (int k0 = 0; k0 < Kd; k0 += 32) {
    __syncthreads();
#pragma unroll
    for (int i = 0; i < TM / 64; i++) {
      int c = t + i * 256;
      int row = c >> 2, ch = c & 3;
      GLD16(A + (size_t)(m0 + row) * Kd + k0 + ch * 8, &a_s[c * 8]);
    }
#pragma unroll
    for (int i = 0; i < 2; i++) {
      int c = t + i * 256;
      int row = c >> 2, ch = c & 3;
      GLD16(BT + (size_t)(n0 + row) * Kd + k0 + ch * 8, &b_s[c * 8]);
    }
    __syncthreads();
    bf16x8 af[MT], bfm[4];
#pragma unroll
    for (int mt = 0; mt < MT; mt++) af[mt] = *(const bf16x8*)&a_s[(wm + mt * 16 + l15) * 32 + quad * 8];
#pragma unroll
    for (int nt = 0; nt < 4; nt++) bfm[nt] = *(const bf16x8*)&b_s[(wn + nt * 16 + l15) * 32 + quad * 8];
#pragma unroll
    for (int mt = 0; mt < MT; mt++)
#pragma unroll
      for (int nt = 0; nt < 4; nt++)
        acc[mt][nt] = __builtin_amdgcn_mfma_f32_16x16x32_bf16(af[mt], bfm[nt], acc[mt][nt], 0, 0, 0);
  }

#pragma unroll
  for (int nt = 0; nt < 4; nt++) {
    int col = n0 + wn + nt * 16 + l15;
    float bv = bias[col];
#pragma unroll
    for (int mt = 0; mt < MT; mt++) {
#pragma unroll
      for (int r = 0; r < 4; r++) {
        int rw = m0 + wm + mt * 16 + quad * 4 + r;
        float v = acc[mt][nt][r] + bv;
        size_t off = (size_t)rw * N + col;
        if (EPI == 0) {
          ((float*)Cout)[off] = v;
        } else if (EPI == 1) {
          ((float*)Cout)[off] = v + resid[off];
        } else if (EPI == 2) {
          ((u16*)Cout)[off] = f2b(0.5f * v * (1.f + erff(v * 0.70710678118654752f)));
        } else {
          ((u16*)Cout)[off] = f2b(v);
        }
      }
    }
  }
}

// ------- RoPE + reorg qkv[BS][1536] bf16 -> Q,K,V [B*H][S][HD] bf16 --------
// Q pre-scaled by (1/sqrt(HD)) * log2(e) so attention can use exp2.
#define QSCALE 0.18033688f
__global__ __launch_bounds__(256) void rope_k(const u16* __restrict__ qkv,
    const float* __restrict__ C, const float* __restrict__ Sn,
    u16* __restrict__ Qo, u16* __restrict__ Ko, u16* __restrict__ Vo) {
  int idx = blockIdx.x * 256 + threadIdx.x;   // one 8-elem chunk
  int row = idx / 192;                        // (b*SEQ + s)
  int cn = idx - row * 192;
  int n0 = cn * 8;
  int comp = n0 >> 9;
  int hh = (n0 >> 6) & 7;
  int d0 = n0 & 63;
  int b = row >> 11, s = row & 2047;
  const u16* src = qkv + (size_t)row * NQKV;
  uint4 val = *(const uint4*)(src + n0);
  u16* vs = (u16*)&val;
  size_t oo = ((size_t)((b << 3) + hh) * SEQ + s) * HD + d0;
  if (comp == 2) { *(uint4*)(Vo + oo) = val; return; }
  uint4 pv = *(const uint4*)(src + (n0 ^ 32));        // rotate-half partner
  u16* ps = (u16*)&pv;
  float cv[8], sv[8];
  *(float4*)&cv[0] = *(const float4*)(C + s * HD + d0);
  *(float4*)&cv[4] = *(const float4*)(C + s * HD + d0 + 4);
  *(float4*)&sv[0] = *(const float4*)(Sn + s * HD + d0);
  *(float4*)&sv[4] = *(const float4*)(Sn + s * HD + d0 + 4);
  float sgn = (d0 & 32) ? 1.f : -1.f;
  float sc = (comp == 0) ? QSCALE : 1.f;
  uint4 ov; u16* os = (u16*)&ov;
#pragma unroll
  for (int j = 0; j < 8; j++)
    os[j] = f2b(sc * (b2f(vs[j]) * cv[j] + sgn * b2f(ps[j]) * sv[j]));
  *(uint4*)((comp == 0 ? Qo : Ko) + oo) = ov;
}

// ---------- flash attention, K-split x2, MFMA bf16, sum-softmax ------------
// block = (split, b, h, 128-row q tile); split s covers keys [s*1024,(s+1)*1024).
// Sum-softmax is associative over K -> partials combine by addition (exact).
// Writes unnormalized O (f32) + l partials; combine_k finishes.
__global__ __launch_bounds__(256) void attn_flash_k(const u16* __restrict__ Qg,
    const u16* __restrict__ Kg, const u16* __restrict__ Vg,
    float* __restrict__ Op, float* __restrict__ Lp) {
  __shared__ u16 q_s[128 * 72];    // Q tile, then P (rows = q rows)
  __shared__ u16 k_s[64 * 72];
  __shared__ u16 vt_s[64 * 72];    // V^T with XOR-swizzled k-blocks
  int t = threadIdx.x, lane = t & 63, w = t >> 6;
  int l15 = lane & 15, quad = lane >> 4;
  int lid = blockIdx.x;                      // 1024 blocks
  int nid = (lid & 7) * 128 + (lid >> 3);    // XCD-contiguous remap
  int split = nid & 1;
  int rest = nid >> 1;
  int bh = rest >> 4;                        // 16 q-tiles per (b,h)
  int qt0 = (rest & 15) * 128;
  int b = bh >> 3, h = bh & 7;
  int kbase = split * (SEQ / 2);
  const u16* Qp = Qg + (size_t)bh * SEQ * HD;
  const u16* Kp = Kg + (size_t)bh * SEQ * HD;
  const u16* Vp = Vg + (size_t)bh * SEQ * HD;
  int row0 = t >> 3, ch = t & 7;   // K/V staging: rows 0..31 (+32)
  int row1 = row0 + 32;
  int r8a = row0 >> 3, r0a = row0 & 7;
  int r8b = row1 >> 3, r0b = row1 & 7;

  // stage Q tile (128 rows)
#pragma unroll
  for (int i = 0; i < 4; i++) {
    int c = t + i * 256, qr = c >> 3, qc = c & 7;
    *(uint4*)&q_s[qr * 72 + qc * 8] = *(const uint4*)(Qp + (size_t)(qt0 + qr) * HD + qc * 8);
  }
  // prefetch first K/V tile of this split into registers
  uint4 kr0 = *(const uint4*)(Kp + (size_t)(kbase + row0) * HD + ch * 8);
  uint4 kr1 = *(const uint4*)(Kp + (size_t)(kbase + row1) * HD + ch * 8);
  uint4 vr0 = *(const uint4*)(Vp + (size_t)(kbase + row0) * HD + ch * 8);
  uint4 vr1 = *(const uint4*)(Vp + (size_t)(kbase + row1) * HD + ch * 8);
  __syncthreads();
  bf16x8 qa[2][2];
#pragma unroll
  for (int rs = 0; rs < 2; rs++) {
    qa[rs][0] = *(const bf16x8*)&q_s[(rs * 64 + w * 16 + l15) * 72 + quad * 8];
    qa[rs][1] = *(const bf16x8*)&q_s[(rs * 64 + w * 16 + l15) * 72 + 32 + quad * 8];
  }
  u16* p_s = q_s;                  // q_s dead after qa load
  f32x4 z4 = {0.f, 0.f, 0.f, 0.f};
  f32x4 of[2][4];
#pragma unroll
  for (int rs = 0; rs < 2; rs++)
#pragma unroll
    for (int n = 0; n < 4; n++) of[rs][n] = z4;
  float lrun[2][4] = {};

  for (int kt = kbase; kt < kbase + SEQ / 2; kt += 64) {
    __syncthreads();               // prior tile's LDS reads drained
    *(uint4*)&k_s[row0 * 72 + ch * 8] = kr0;
    *(uint4*)&k_s[row1 * 72 + ch * 8] = kr1;
    {
      u16* v0 = (u16*)&vr0; u16* v1 = (u16*)&vr1;
#pragma unroll
      for (int j = 0; j < 8; j++) {
        int d = ch * 8 + j;        // d>>3 == ch
        vt_s[d * 72 + ((r8a ^ ch) << 3) + r0a] = v0[j];
        vt_s[d * 72 + ((r8b ^ ch) << 3) + r0b] = v1[j];
      }
    }
    __syncthreads();               // staging visible
    if (kt + 64 < kbase + SEQ / 2) {   // prefetch next tile
      kr0 = *(const uint4*)(Kp + (size_t)(kt + 64 + row0) * HD + ch * 8);
      kr1 = *(const uint4*)(Kp + (size_t)(kt + 64 + row1) * HD + ch * 8);
      vr0 = *(const uint4*)(Vp + (size_t)(kt + 64 + row0) * HD + ch * 8);
      vr1 = *(const uint4*)(Vp + (size_t)(kt + 64 + row1) * HD + ch * 8);
    }
    // S = Q K^T: sf[rs][n] = S[q=rs*64+w*16+quad*4+r][key=n*16+l15]
    f32x4 sf[2][4];
#pragma unroll
    for (int rs = 0; rs < 2; rs++)
#pragma unroll
      for (int n = 0; n < 4; n++) sf[rs][n] = z4;
#pragma unroll
    for (int kk = 0; kk < 2; kk++)
#pragma unroll
      for (int n = 0; n < 4; n++) {
        bf16x8 kb = *(const bf16x8*)&k_s[(n * 16 + l15) * 72 + kk * 32 + quad * 8];
        sf[0][n] = __builtin_amdgcn_mfma_f32_16x16x32_bf16(qa[0][kk], kb, sf[0][n], 0, 0, 0);
        sf[1][n] = __builtin_amdgcn_mfma_f32_16x16x32_bf16(qa[1][kk], kb, sf[1][n], 0, 0, 0);
      }
    // p = exp2(s) (Q carried log2e/8); store RTZ bf16; defer normalization
#pragma unroll
    for (int rs = 0; rs < 2; rs++)
#pragma unroll
      for (int r = 0; r < 4; r++) {
        int prow = (rs * 64 + w * 16 + quad * 4 + r) * 72;
#pragma unroll
        for (int n = 0; n < 4; n++) {
          float pp = exp2f(sf[rs][n][r]);
          lrun[rs][r] += pp;
          p_s[prow + n * 16 + l15] = f2b_rtz(pp);
        }
      }
    // O += P V
#pragma unroll
    for (int kk = 0; kk < 2; kk++) {
      bf16x8 pa0 = *(const bf16x8*)&p_s[(w * 16 + l15) * 72 + kk * 32 + quad * 8];
      bf16x8 pa1 = *(const bf16x8*)&p_s[(64 + w * 16 + l15) * 72 + kk * 32 + quad * 8];
#pragma unroll
      for (int n = 0; n < 4; n++) {
        bf16x8 vb = *(const bf16x8*)&vt_s[(n * 16 + l15) * 72 +
                     (((kk * 4 + quad) ^ (2 * n + (l15 >> 3))) << 3)];
        of[0][n] = __builtin_amdgcn_mfma_f32_16x16x32_bf16(pa0, vb, of[0][n], 0, 0, 0);
        of[1][n] = __builtin_amdgcn_mfma_f32_16x16x32_bf16(pa1, vb, of[1][n], 0, 0, 0);
      }
    }
  }
  // epilogue: unnormalized O partial (f32) + l partial
  float* Ob = Op + (size_t)split * BS * DIMM;
  float* Lb = Lp + (size_t)split * (BS * NH / 8);   // 65536 per split
#pragma unroll
  for (int rs = 0; rs < 2; rs++)
#pragma unroll
    for (int r = 0; r < 4; r++) {
      int qrow = qt0 + rs * 64 + w * 16 + quad * 4 + r;
      float l = lrun[rs][r];
#pragma unroll
      for (int m = 1; m < 16; m <<= 1) l += __shfl_xor(l, m);
      if (l15 == 0) Lb[(size_t)bh * SEQ + qrow] = l;
      size_t orow = (size_t)(b * SEQ + qrow);
#pragma unroll
      for (int n = 0; n < 4; n++)
        Ob[orow * DIMM + h * HD + n * 16 + l15] = of[rs][n][r];
    }
}

// ---------------- combine K-split partials -> bf16 ob ----------------------
__global__ __launch_bounds__(256) void combine_k(const float* __restrict__ Op,
    const float* __restrict__ Lp, u16* __restrict__ ob) {
  int idx = (blockIdx.x * 256 + threadIdx.x) * 4;    // element base
  int row = idx >> 9, col = idx & 511;
  int b = row >> 11, q = row & 2047, h = col >> 6;
  size_t li = (size_t)(b * NH + h) * SEQ + q;
  float inv = 1.f / (Lp[li] + Lp[(size_t)BS * NH / 8 * 1 + li]);
  float4 o1 = *(const float4*)(Op + (size_t)idx);
  float4 o2 = *(const float4*)(Op + (size_t)BS * DIMM + idx);
  u16x4 ov;
  ov[0] = f2b((o1.x + o2.x) * inv);
  ov[1] = f2b((o1.y + o2.y) * inv);
  ov[2] = f2b((o1.z + o2.z) * inv);
  ov[3] = f2b((o1.w + o2.w) * inv);
  *(u16x4*)(ob + idx) = ov;
}

// ---------------------------------------------------------------------------
extern "C" void kernel_launch(void* const* d_in, const int* in_sizes, int n_in,
                              void* d_out, int out_size, void* d_ws, size_t ws_size,
                              hipStream_t stream) {
  const float* x    = (const float*)d_in[0];
  const float* rc   = (const float*)d_in[1];
  const float* rsn  = (const float*)d_in[2];
  const float* n1g  = (const float*)d_in[3];
  const float* n1b  = (const float*)d_in[4];
  const float* n2g  = (const float*)d_in[5];
  const float* n2b  = (const float*)d_in[6];
  const float* wqkv = (const float*)d_in[7];
  const float* bqkv = (const float*)d_in[8];
  const float* wprj = (const float*)d_in[9];
  const float* bprj = (const float*)d_in[10];
  const float* wf1  = (const float*)d_in[11];
  const float* bf1  = (const float*)d_in[12];
  const float* wf2  = (const float*)d_in[13];
  const float* bf2  = (const float*)d_in[14];

  char* p = (char*)d_ws;
  u16*   wqkvT = (u16*)p;                   // 1.5 MB
  u16*   wprjT = (u16*)(p + (2u  << 20));   // 0.5 MB
  u16*   wf1T  = (u16*)(p + (3u  << 20));   // 2 MB
  u16*   wf2T  = (u16*)(p + (5u  << 20));   // 2 MB
  u16*   h1    = (u16*)(p + (8u  << 20));   // 8 MB bf16: LN1 out / ob / h2
  u16*   qkvb  = (u16*)(p + (16u << 20));   // 24 MB bf16 (dead after rope)
  float* Opart = (float*)(p + (16u << 20)); // 32 MB f32 [2][BS][DIMM] (attn)
  float* Lpart = (float*)(p + (48u << 20)); // 0.5 MB f32 [2][B*NH][SEQ]
  u16*   Qb    = (u16*)(p + (64u << 20));   // 8 MB bf16
  u16*   Kb    = (u16*)(p + (72u << 20));   // 8 MB bf16
  u16*   Vb    = (u16*)(p + (80u << 20));   // 8 MB bf16
  float* x2    = (float*)(p + (88u << 20)); // 16 MB f32 residual stream
  u16*   ob    = h1;                        // h1 dead after QKV gemm
  u16*   h2    = h1;                        // ob dead after proj gemm
  u16*   mid   = qkvb;                      // 32 MB bf16 region (Opart dead by fc1)

  transpose_all_k<<<dim3((SZ_QKV + SZ_PRJ + SZ_F1 + SZ_F2) / 256), 256, 0, stream>>>(
      wqkv, wprj, wf1, wf2, wqkvT, wprjT, wf1T, wf2T);

  ln_f32b_k<<<dim3(BS / 4), 256, 0, stream>>>(x, n1g, n1b, h1);

  gemm_bt<3, 128><<<dim3(NQKV / 128, BS / 128), 256, 0, stream>>>(h1, wqkvT, bqkv, qkvb, nullptr, NQKV, DIMM);

  rope_k<<<dim3(BS * NQKV / 8 / 256), 256, 0, stream>>>(qkvb, rc, rsn, Qb, Kb, Vb);

  attn_flash_k<<<dim3(2 * 32 * (SEQ / 128)), 256, 0, stream>>>(Qb, Kb, Vb, Opart, Lpart);

  combine_k<<<dim3(BS * DIMM / 4 / 256), 256, 0, stream>>>(Opart, Lpart, ob);

  gemm_bt<1, 64><<<dim3(DIMM / 128, BS / 64), 256, 0, stream>>>(ob, wprjT, bprj, x2, x, DIMM, DIMM);

  ln_f32b_k<<<dim3(BS / 4), 256, 0, stream>>>(x2, n2g, n2b, h2);

  gemm_bt<2, 128><<<dim3(DFF / 128, BS / 128), 256, 0, stream>>>(h2, wf1T, bf1, mid, nullptr, DFF, DIMM);

  gemm_bt<1, 64><<<dim3(DIMM / 128, BS / 64), 256, 0, stream>>>(mid, wf2T, bf2, (float*)d_out, x2, DIMM, DFF);
}